// Round 1
// baseline (201.233 us; speedup 1.0000x reference)
//
#include <hip/hip_runtime.h>
#include <hip/hip_bf16.h>
#include <stdint.h>
#include <math.h>

#define NN 8192
#define MM 8192
#define DD 256
#define NPART ((NN / 128) * (MM / 128))  // 4096 blocks

typedef __attribute__((ext_vector_type(8))) short short8;
typedef __attribute__((ext_vector_type(4))) float float4v;
typedef __attribute__((ext_vector_type(4))) unsigned short ushort4v;

__device__ __forceinline__ unsigned short f2bf_rn(float f) {
  union { float ff; unsigned u; } v; v.ff = f;
  unsigned r = v.u + 0x7FFFu + ((v.u >> 16) & 1u);  // round-to-nearest-even
  return (unsigned short)(r >> 16);
}

__global__ void convert_f32_bf16(const float* __restrict__ in,
                                 unsigned short* __restrict__ out, int n4) {
  int i = blockIdx.x * blockDim.x + threadIdx.x;
  const int stride = gridDim.x * blockDim.x;
  for (; i < n4; i += stride) {
    float4v x = ((const float4v*)in)[i];
    ushort4v o;
    o[0] = f2bf_rn(x[0]); o[1] = f2bf_rn(x[1]);
    o[2] = f2bf_rn(x[2]); o[3] = f2bf_rn(x[3]);
    ((ushort4v*)out)[i] = o;
  }
}

__device__ __forceinline__ short8 pack8(float4v a0, float4v a1) {
  short8 r;
  r[0] = (short)f2bf_rn(a0[0]); r[1] = (short)f2bf_rn(a0[1]);
  r[2] = (short)f2bf_rn(a0[2]); r[3] = (short)f2bf_rn(a0[3]);
  r[4] = (short)f2bf_rn(a1[0]); r[5] = (short)f2bf_rn(a1[1]);
  r[6] = (short)f2bf_rn(a1[2]); r[7] = (short)f2bf_rn(a1[3]);
  return r;
}

// 128x128 tile, BK=64, 4 waves (2x2), each wave 64x64 via 4x4 mfma_f32_16x16x32_bf16.
// LDS layout: [row][k] rows of 128B, XOR-swizzled: phys_kbyte = kbyte ^ ((row&7)<<4).
// Staging: global_load_lds(16B) with pre-swizzled GLOBAL source + linear LDS dest (rule #21).
template <bool BF16WS>
__global__ __launch_bounds__(256) void gemm_sigloss(
    const unsigned short* __restrict__ Abf, const unsigned short* __restrict__ Bbf,
    const float* __restrict__ A32, const float* __restrict__ B32,
    const int* __restrict__ la, const int* __restrict__ lb,
    const float* __restrict__ scale_p, const float* __restrict__ bias_p,
    float* __restrict__ pos_part, float* __restrict__ neg_part,
    unsigned* __restrict__ cnt_part) {
  __shared__ unsigned short As[128 * 64];
  __shared__ unsigned short Bs[128 * 64];
  __shared__ float redp[4], redn[4];
  __shared__ unsigned redc[4];

  const int tid = threadIdx.x;
  const int w = tid >> 6;
  const int l = tid & 63;
  const int bid = blockIdx.x;
  const int brow = (bid >> 6) << 7;
  const int bcol = (bid & 63) << 7;
  const int wrow = (w >> 1) << 6;
  const int wcol = (w & 1) << 6;
  const int col16 = l & 15;
  const int quad = l >> 4;

  float4v acc[4][4];
#pragma unroll
  for (int i = 0; i < 4; ++i)
#pragma unroll
    for (int j = 0; j < 4; ++j) acc[i][j] = (float4v){0.f, 0.f, 0.f, 0.f};

  // staging geometry: each wave covers 32 rows per operand per K-step, in 4 issues of
  // 8 rows x 64 lanes x 16B. lane l -> row group rg = l>>3, 16B chunk c8 = l&7.
  // swizzled source k-offset (elements): ((c8*16) ^ (rg<<4)) / 2
  const int rg = l >> 3;
  const int c8 = l & 7;
  const int ksw = (c8 ^ rg) << 3;

  for (int kt = 0; kt < DD / 64; ++kt) {
    const int k0 = kt << 6;
#pragma unroll
    for (int i = 0; i < 4; ++i) {
      const int trow = (w << 5) + (i << 3) + rg;  // tile row 0..127; trow&7 == rg
      const size_t ga = (size_t)(brow + trow) * DD + k0 + ksw;
      const size_t gb = (size_t)(bcol + trow) * DD + k0 + ksw;
      const int lofs = ((w << 2) + i) << 9;  // issue base, elements (512 bf16 = 1KB)
      if constexpr (BF16WS) {
        __builtin_amdgcn_global_load_lds(
            (const __attribute__((address_space(1))) void*)(Abf + ga),
            (__attribute__((address_space(3))) void*)(&As[lofs]), 16, 0, 0);
        __builtin_amdgcn_global_load_lds(
            (const __attribute__((address_space(1))) void*)(Bbf + gb),
            (__attribute__((address_space(3))) void*)(&Bs[lofs]), 16, 0, 0);
      } else {
        const float4v* pa = (const float4v*)(A32 + ga);
        const float4v* pb = (const float4v*)(B32 + gb);
        float4v a0 = pa[0], a1 = pa[1];
        float4v b0 = pb[0], b1 = pb[1];
        *(short8*)((char*)As + (size_t)lofs * 2 + (size_t)l * 16) = pack8(a0, a1);
        *(short8*)((char*)Bs + (size_t)lofs * 2 + (size_t)l * 16) = pack8(b0, b1);
      }
    }
    __syncthreads();
#pragma unroll
    for (int kk = 0; kk < 2; ++kk) {
      const int kb = (kk << 6) + (quad << 4);  // byte offset in 128B row
      const int sw = (col16 & 7) << 4;
      short8 af[4], bfv[4];
#pragma unroll
      for (int mi = 0; mi < 4; ++mi) {
        const int row = wrow + (mi << 4) + col16;
        af[mi] = *(const short8*)((const char*)As + row * 128 + (kb ^ sw));
      }
#pragma unroll
      for (int ni = 0; ni < 4; ++ni) {
        const int row = wcol + (ni << 4) + col16;
        bfv[ni] = *(const short8*)((const char*)Bs + row * 128 + (kb ^ sw));
      }
#pragma unroll
      for (int mi = 0; mi < 4; ++mi)
#pragma unroll
        for (int ni = 0; ni < 4; ++ni)
          acc[mi][ni] = __builtin_amdgcn_mfma_f32_16x16x32_bf16(
              af[mi], bfv[ni], acc[mi][ni], 0, 0, 0);
    }
    __syncthreads();
  }

  // ---- fused epilogue: loss = softplus(-(labels*logits)), split pos/neg ----
  const float scale = *scale_p;
  const float bias = *bias_p;
  float ps = 0.f, ns = 0.f;
  int pc = 0;

  int lbv[4];
#pragma unroll
  for (int ni = 0; ni < 4; ++ni) lbv[ni] = lb[bcol + wcol + (ni << 4) + col16];

#pragma unroll
  for (int mi = 0; mi < 4; ++mi) {
#pragma unroll
    for (int r = 0; r < 4; ++r) {
      const int grow = brow + wrow + (mi << 4) + (quad << 2) + r;
      const int lav = la[grow];
#pragma unroll
      for (int ni = 0; ni < 4; ++ni) {
        const float logit = fmaf(scale, acc[mi][ni][r], bias);
        const bool match = (lav == lbv[ni]);
        const float t = match ? -logit : logit;  // t = -labels*logits
        const float lossv = fmaxf(t, 0.f) + log1pf(__expf(-fabsf(t)));
        ps += match ? lossv : 0.f;
        ns += match ? 0.f : lossv;
        pc += match ? 1 : 0;
      }
    }
  }

  // deterministic per-block partials (no float atomics)
#pragma unroll
  for (int off = 32; off > 0; off >>= 1) {
    ps += __shfl_down(ps, off);
    ns += __shfl_down(ns, off);
    pc += __shfl_down(pc, off);
  }
  if (l == 0) { redp[w] = ps; redn[w] = ns; redc[w] = (unsigned)pc; }
  __syncthreads();
  if (tid == 0) {
    pos_part[bid] = redp[0] + redp[1] + redp[2] + redp[3];
    neg_part[bid] = redn[0] + redn[1] + redn[2] + redn[3];
    cnt_part[bid] = redc[0] + redc[1] + redc[2] + redc[3];
  }
}

__global__ __launch_bounds__(256) void finalize_loss(
    const float* __restrict__ pos_part, const float* __restrict__ neg_part,
    const unsigned* __restrict__ cnt_part, float* __restrict__ out) {
  __shared__ float rp[4], rn[4];
  __shared__ unsigned rc[4];
  const int w = threadIdx.x >> 6;
  const int l = threadIdx.x & 63;
  float ps = 0.f, ns = 0.f;
  int pc = 0;
  for (int i = threadIdx.x; i < NPART; i += 256) {
    ps += pos_part[i];
    ns += neg_part[i];
    pc += (int)cnt_part[i];
  }
#pragma unroll
  for (int off = 32; off > 0; off >>= 1) {
    ps += __shfl_down(ps, off);
    ns += __shfl_down(ns, off);
    pc += __shfl_down(pc, off);
  }
  if (l == 0) { rp[w] = ps; rn[w] = ns; rc[w] = (unsigned)pc; }
  __syncthreads();
  if (threadIdx.x == 0) {
    double tp = (double)rp[0] + rp[1] + rp[2] + rp[3];
    double tn = (double)rn[0] + rn[1] + rn[2] + rn[3];
    long long tc = (long long)rc[0] + rc[1] + rc[2] + rc[3];
    double num_pos = (double)(tc > 1 ? tc : 1);
    long long negc = (long long)NN * MM - tc;
    double num_neg = (double)(negc > 1 ? negc : 1);
    out[0] = (float)(tp / num_pos + tn / num_neg * (double)(NN - 1));
  }
}

extern "C" void kernel_launch(void* const* d_in, const int* in_sizes, int n_in,
                              void* d_out, int out_size, void* d_ws, size_t ws_size,
                              hipStream_t stream) {
  const float* A32 = (const float*)d_in[0];
  const float* B32 = (const float*)d_in[1];
  const int* la = (const int*)d_in[2];
  const int* lb = (const int*)d_in[3];
  const float* scale_p = (const float*)d_in[4];
  const float* bias_p = (const float*)d_in[5];
  float* out = (float*)d_out;

  char* ws = (char*)d_ws;
  float* pos_part = (float*)ws;                       // 4096 f32
  float* neg_part = pos_part + NPART;                 // 4096 f32
  unsigned* cnt_part = (unsigned*)(neg_part + NPART); // 4096 u32
  unsigned short* Abf = (unsigned short*)(ws + 65536);
  unsigned short* Bbf = Abf + (size_t)NN * DD;

  const size_t need = 65536 + 2ull * (size_t)NN * DD * 2;
  const bool usebf = (ws_size >= need);

  if (usebf) {
    const int n4 = NN * DD / 4;  // 524288
    convert_f32_bf16<<<2048, 256, 0, stream>>>(A32, Abf, n4);
    convert_f32_bf16<<<2048, 256, 0, stream>>>(B32, Bbf, n4);
    gemm_sigloss<true><<<NPART, 256, 0, stream>>>(Abf, Bbf, A32, B32, la, lb,
                                                  scale_p, bias_p, pos_part,
                                                  neg_part, cnt_part);
  } else {
    gemm_sigloss<false><<<NPART, 256, 0, stream>>>(nullptr, nullptr, A32, B32, la,
                                                   lb, scale_p, bias_p, pos_part,
                                                   neg_part, cnt_part);
  }
  finalize_loss<<<1, 256, 0, stream>>>(pos_part, neg_part, cnt_part, out);
}

// Round 3
// 82.452 us; speedup vs baseline: 2.4406x; 2.4406x over previous
//
#include <hip/hip_runtime.h>
#include <hip/hip_bf16.h>
#include <stdint.h>
#include <math.h>

#define NN 8192
#define MM 8192
#define DD 256
#define NPART ((NN / 128) * (MM / 128))  // 4096 blocks

typedef __attribute__((ext_vector_type(8))) short short8;
typedef __attribute__((ext_vector_type(4))) float float4v;
typedef __attribute__((ext_vector_type(2))) unsigned uint2v;

__device__ __forceinline__ unsigned cvt_pk_bf16(float lo, float hi) {
  unsigned r;
  asm("v_cvt_pk_bf16_f32 %0, %1, %2" : "=v"(r) : "v"(lo), "v"(hi));
  return r;
}

__global__ void convert_f32_bf16(const float* __restrict__ in,
                                 unsigned short* __restrict__ out, int n4) {
  int i = blockIdx.x * blockDim.x + threadIdx.x;
  const int stride = gridDim.x * blockDim.x;
  for (; i < n4; i += stride) {
    float4v x = ((const float4v*)in)[i];
    uint2v o;
    o[0] = cvt_pk_bf16(x[0], x[1]);
    o[1] = cvt_pk_bf16(x[2], x[3]);
    ((uint2v*)out)[i] = o;
  }
}

__device__ __forceinline__ short8 pack8(float4v a0, float4v a1) {
  union { short8 s; unsigned u[4]; } r;
  r.u[0] = cvt_pk_bf16(a0[0], a0[1]);
  r.u[1] = cvt_pk_bf16(a0[2], a0[3]);
  r.u[2] = cvt_pk_bf16(a1[0], a1[1]);
  r.u[3] = cvt_pk_bf16(a1[2], a1[3]);
  return r.s;
}

// fast stable softplus(t) = max(t,0) + log(1+exp(-|t|)) via v_exp_f32/v_log_f32
__device__ __forceinline__ float softplus_fast(float t) {
  return fmaxf(t, 0.f) + __logf(1.f + __expf(-fabsf(t)));
}

// 128x128 tile, BK=64, 4 waves (2x2), each wave 64x64 via 4x4 mfma_f32_16x16x32_bf16.
// LDS layout: [row][k] rows of 128B, XOR-swizzled: phys_kbyte = kbyte ^ ((row&7)<<4).
// Staging: global_load_lds(16B) with pre-swizzled GLOBAL source + linear LDS dest.
template <bool BF16WS>
__device__ __forceinline__ void gemm_sigloss_body(
    const unsigned short* __restrict__ Abf, const unsigned short* __restrict__ Bbf,
    const float* __restrict__ A32, const float* __restrict__ B32,
    const int* __restrict__ la, const int* __restrict__ lb,
    const float* __restrict__ scale_p, const float* __restrict__ bias_p,
    float* __restrict__ pos_part, float* __restrict__ neg_part,
    unsigned* __restrict__ cnt_part) {
  __shared__ unsigned short As[128 * 64];
  __shared__ unsigned short Bs[128 * 64];
  __shared__ float redp[4], redn[4];
  __shared__ unsigned redc[4];

  const int tid = threadIdx.x;
  const int w = tid >> 6;
  const int l = tid & 63;
  // bijective XCD swizzle: 4096 % 8 == 0
  const int bid = ((blockIdx.x & 7) << 9) + (blockIdx.x >> 3);
  const int brow = (bid >> 6) << 7;
  const int bcol = (bid & 63) << 7;
  const int wrow = (w >> 1) << 6;
  const int wcol = (w & 1) << 6;
  const int col16 = l & 15;
  const int quad = l >> 4;

  float4v acc[4][4];
#pragma unroll
  for (int i = 0; i < 4; ++i)
#pragma unroll
    for (int j = 0; j < 4; ++j) acc[i][j] = (float4v){0.f, 0.f, 0.f, 0.f};

  // staging: lane l -> row group rg = l>>3, 16B chunk c8 = l&7.
  const int rg = l >> 3;
  const int c8 = l & 7;
  const int ksw = (c8 ^ rg) << 3;  // swizzled k-offset in elements

  for (int kt = 0; kt < DD / 64; ++kt) {
    const int k0 = kt << 6;
#pragma unroll
    for (int i = 0; i < 4; ++i) {
      const int trow = (w << 5) + (i << 3) + rg;  // tile row 0..127; trow&7 == rg
      const size_t ga = (size_t)(brow + trow) * DD + k0 + ksw;
      const size_t gb = (size_t)(bcol + trow) * DD + k0 + ksw;
      const int lofs = ((w << 2) + i) << 9;  // issue base, elements
      if constexpr (BF16WS) {
        __builtin_amdgcn_global_load_lds(
            (const __attribute__((address_space(1))) void*)(Abf + ga),
            (__attribute__((address_space(3))) void*)(&As[lofs]), 16, 0, 0);
        __builtin_amdgcn_global_load_lds(
            (const __attribute__((address_space(1))) void*)(Bbf + gb),
            (__attribute__((address_space(3))) void*)(&Bs[lofs]), 16, 0, 0);
      } else {
        const float4v* pa = (const float4v*)(A32 + ga);
        const float4v* pb = (const float4v*)(B32 + gb);
        float4v a0 = pa[0], a1 = pa[1];
        float4v b0 = pb[0], b1 = pb[1];
        *(short8*)((char*)As + (size_t)lofs * 2 + (size_t)l * 16) = pack8(a0, a1);
        *(short8*)((char*)Bs + (size_t)lofs * 2 + (size_t)l * 16) = pack8(b0, b1);
      }
    }
    __syncthreads();
#pragma unroll
    for (int kk = 0; kk < 2; ++kk) {
      const int kb = (kk << 6) + (quad << 4);  // byte offset in 128B row
      const int sw = (col16 & 7) << 4;
      short8 af[4], bfv[4];
#pragma unroll
      for (int mi = 0; mi < 4; ++mi) {
        const int row = wrow + (mi << 4) + col16;
        af[mi] = *(const short8*)((const char*)As + row * 128 + (kb ^ sw));
      }
#pragma unroll
      for (int ni = 0; ni < 4; ++ni) {
        const int row = wcol + (ni << 4) + col16;
        bfv[ni] = *(const short8*)((const char*)Bs + row * 128 + (kb ^ sw));
      }
#pragma unroll
      for (int mi = 0; mi < 4; ++mi)
#pragma unroll
        for (int ni = 0; ni < 4; ++ni)
          acc[mi][ni] = __builtin_amdgcn_mfma_f32_16x16x32_bf16(
              af[mi], bfv[ni], acc[mi][ni], 0, 0, 0);
    }
    __syncthreads();
  }

  // ---- fused epilogue: loss = softplus(-(labels*logits)), split pos/neg ----
  const float scale = *scale_p;
  const float bias = *bias_p;
  float ps = 0.f, ns = 0.f;
  int pc = 0;

  int lbv[4];
#pragma unroll
  for (int ni = 0; ni < 4; ++ni) lbv[ni] = lb[bcol + wcol + (ni << 4) + col16];

#pragma unroll
  for (int mi = 0; mi < 4; ++mi) {
#pragma unroll
    for (int r = 0; r < 4; ++r) {
      const int grow = brow + wrow + (mi << 4) + (quad << 2) + r;
      const int lav = la[grow];
#pragma unroll
      for (int ni = 0; ni < 4; ++ni) {
        const float logit = fmaf(scale, acc[mi][ni][r], bias);
        const bool match = (lav == lbv[ni]);
        const float t = match ? -logit : logit;  // t = -labels*logits
        const float lossv = softplus_fast(t);
        ps += match ? lossv : 0.f;
        ns += match ? 0.f : lossv;
        pc += match ? 1 : 0;
      }
    }
  }

  // deterministic per-block partials (no float atomics)
#pragma unroll
  for (int off = 32; off > 0; off >>= 1) {
    ps += __shfl_down(ps, off);
    ns += __shfl_down(ns, off);
    pc += __shfl_down(pc, off);
  }
  if (l == 0) { redp[w] = ps; redn[w] = ns; redc[w] = (unsigned)pc; }
  __syncthreads();
  if (tid == 0) {
    pos_part[bid] = redp[0] + redp[1] + redp[2] + redp[3];
    neg_part[bid] = redn[0] + redn[1] + redn[2] + redn[3];
    cnt_part[bid] = redc[0] + redc[1] + redc[2] + redc[3];
  }
}

__global__ __launch_bounds__(256) void gemm_sigloss_bf16ws(
    const unsigned short* __restrict__ Abf, const unsigned short* __restrict__ Bbf,
    const int* __restrict__ la, const int* __restrict__ lb,
    const float* __restrict__ scale_p, const float* __restrict__ bias_p,
    float* __restrict__ pos_part, float* __restrict__ neg_part,
    unsigned* __restrict__ cnt_part) {
  gemm_sigloss_body<true>(Abf, Bbf, nullptr, nullptr, la, lb, scale_p, bias_p,
                          pos_part, neg_part, cnt_part);
}

__global__ __launch_bounds__(256) void gemm_sigloss_f32(
    const float* __restrict__ A32, const float* __restrict__ B32,
    const int* __restrict__ la, const int* __restrict__ lb,
    const float* __restrict__ scale_p, const float* __restrict__ bias_p,
    float* __restrict__ pos_part, float* __restrict__ neg_part,
    unsigned* __restrict__ cnt_part) {
  gemm_sigloss_body<false>(nullptr, nullptr, A32, B32, la, lb, scale_p, bias_p,
                           pos_part, neg_part, cnt_part);
}

__global__ __launch_bounds__(256) void finalize_loss(
    const float* __restrict__ pos_part, const float* __restrict__ neg_part,
    const unsigned* __restrict__ cnt_part, float* __restrict__ out) {
  __shared__ float rp[4], rn[4];
  __shared__ unsigned rc[4];
  const int w = threadIdx.x >> 6;
  const int l = threadIdx.x & 63;
  float ps = 0.f, ns = 0.f;
  int pc = 0;
  for (int i = threadIdx.x; i < NPART; i += 256) {
    ps += pos_part[i];
    ns += neg_part[i];
    pc += (int)cnt_part[i];
  }
#pragma unroll
  for (int off = 32; off > 0; off >>= 1) {
    ps += __shfl_down(ps, off);
    ns += __shfl_down(ns, off);
    pc += __shfl_down(pc, off);
  }
  if (l == 0) { rp[w] = ps; rn[w] = ns; rc[w] = (unsigned)pc; }
  __syncthreads();
  if (threadIdx.x == 0) {
    double tp = (double)rp[0] + rp[1] + rp[2] + rp[3];
    double tn = (double)rn[0] + rn[1] + rn[2] + rn[3];
    long long tc = (long long)rc[0] + rc[1] + rc[2] + rc[3];
    double num_pos = (double)(tc > 1 ? tc : 1);
    long long negc = (long long)NN * MM - tc;
    double num_neg = (double)(negc > 1 ? negc : 1);
    out[0] = (float)(tp / num_pos + tn / num_neg * (double)(NN - 1));
  }
}

extern "C" void kernel_launch(void* const* d_in, const int* in_sizes, int n_in,
                              void* d_out, int out_size, void* d_ws, size_t ws_size,
                              hipStream_t stream) {
  const float* A32 = (const float*)d_in[0];
  const float* B32 = (const float*)d_in[1];
  const int* la = (const int*)d_in[2];
  const int* lb = (const int*)d_in[3];
  const float* scale_p = (const float*)d_in[4];
  const float* bias_p = (const float*)d_in[5];
  float* out = (float*)d_out;

  char* ws = (char*)d_ws;
  float* pos_part = (float*)ws;                       // 4096 f32
  float* neg_part = pos_part + NPART;                 // 4096 f32
  unsigned* cnt_part = (unsigned*)(neg_part + NPART); // 4096 u32
  unsigned short* Abf = (unsigned short*)(ws + 65536);
  unsigned short* Bbf = Abf + (size_t)NN * DD;

  const size_t need = 65536 + 2ull * (size_t)NN * DD * 2;
  const bool usebf = (ws_size >= need);

  if (usebf) {
    const int n4 = NN * DD / 4;  // 524288
    convert_f32_bf16<<<1024, 256, 0, stream>>>(A32, Abf, n4);
    convert_f32_bf16<<<1024, 256, 0, stream>>>(B32, Bbf, n4);
    gemm_sigloss_bf16ws<<<NPART, 256, 0, stream>>>(Abf, Bbf, la, lb, scale_p,
                                                   bias_p, pos_part, neg_part,
                                                   cnt_part);
  } else {
    gemm_sigloss_f32<<<NPART, 256, 0, stream>>>(A32, B32, la, lb, scale_p,
                                                bias_p, pos_part, neg_part,
                                                cnt_part);
  }
  finalize_loss<<<1, 256, 0, stream>>>(pos_part, neg_part, cnt_part, out);
}

// Round 4
// 77.241 us; speedup vs baseline: 2.6052x; 1.0675x over previous
//
#include <hip/hip_runtime.h>
#include <hip/hip_bf16.h>
#include <stdint.h>
#include <math.h>

#define NN 8192
#define MM 8192
#define DD 256
#define BT 256
#define NPART ((NN / BT) * (MM / BT))  // 1024 blocks
#define LOG2E 1.44269504088896340736f
#define LN2 0.69314718055994530942f

typedef __attribute__((ext_vector_type(8))) short short8;
typedef __attribute__((ext_vector_type(4))) float float4v;
typedef __attribute__((ext_vector_type(2))) unsigned uint2v;

__device__ __forceinline__ unsigned cvt_pk_bf16(float lo, float hi) {
  unsigned r;
  asm("v_cvt_pk_bf16_f32 %0, %1, %2" : "=v"(r) : "v"(lo), "v"(hi));
  return r;
}
__device__ __forceinline__ float fast_exp2(float x) {  // 2^x
  float r;
  asm("v_exp_f32 %0, %1" : "=v"(r) : "v"(x));
  return r;
}
__device__ __forceinline__ float fast_log2(float x) {  // log2(x)
  float r;
  asm("v_log_f32 %0, %1" : "=v"(r) : "v"(x));
  return r;
}

// one kernel converts both A and B (f32 -> bf16), vectorized 4-wide
__global__ void convert_both(const float* __restrict__ A32,
                             const float* __restrict__ B32,
                             unsigned short* __restrict__ Abf,
                             unsigned short* __restrict__ Bbf) {
  const int n4 = NN * DD / 4;  // per array
  const int stride = gridDim.x * blockDim.x;
  for (int idx = blockIdx.x * blockDim.x + threadIdx.x; idx < 2 * n4;
       idx += stride) {
    const bool isA = idx < n4;
    const int j = isA ? idx : idx - n4;
    float4v x = isA ? ((const float4v*)A32)[j] : ((const float4v*)B32)[j];
    uint2v o;
    o[0] = cvt_pk_bf16(x[0], x[1]);
    o[1] = cvt_pk_bf16(x[2], x[3]);
    if (isA) ((uint2v*)Abf)[j] = o;
    else     ((uint2v*)Bbf)[j] = o;
  }
}

__device__ __forceinline__ short8 pack8(float4v a0, float4v a1) {
  union { short8 s; unsigned u[4]; } r;
  r.u[0] = cvt_pk_bf16(a0[0], a0[1]);
  r.u[1] = cvt_pk_bf16(a0[2], a0[3]);
  r.u[2] = cvt_pk_bf16(a1[0], a1[1]);
  r.u[3] = cvt_pk_bf16(a1[2], a1[3]);
  return r.s;
}

// 256x256 tile, BK=64, 8 waves (2Mx4N), per-wave 128x64 via 8x4 mfma_f32_16x16x32_bf16.
// LDS: [256][64] bf16 rows of 128B, double-buffered (2x32KB per operand = 128KB).
// XOR swizzle: phys_kbyte = kbyte ^ ((row&7)<<4); staged via pre-swizzled GLOBAL
// source + linear LDS dest (global_load_lds width 16).
// Pipeline: STAGE(t+1 -> buf^1) issued BEFORE compute(buf); one barrier per K-tile.
template <bool BF16WS>
__device__ __forceinline__ void gemm_sigloss_body(
    const unsigned short* __restrict__ Abf, const unsigned short* __restrict__ Bbf,
    const float* __restrict__ A32, const float* __restrict__ B32,
    const int* __restrict__ la, const int* __restrict__ lb,
    const float* __restrict__ scale_p, const float* __restrict__ bias_p,
    float* __restrict__ pos_part, float* __restrict__ neg_part,
    unsigned* __restrict__ cnt_part) {
  __shared__ unsigned short As[2][BT * 64];
  __shared__ unsigned short Bs[2][BT * 64];
  __shared__ float redp[8], redn[8];
  __shared__ unsigned redc[8];

  const int tid = threadIdx.x;  // 0..511
  const int w = tid >> 6;       // 0..7
  const int l = tid & 63;
  // bijective XCD swizzle: 1024 % 8 == 0
  const int sb = ((blockIdx.x & 7) << 7) | (blockIdx.x >> 3);
  const int brow = (sb >> 5) << 8;
  const int bcol = (sb & 31) << 8;
  const int wr = w >> 2;  // 0..1
  const int wc = w & 3;   // 0..3
  const int col16 = l & 15;
  const int quad = l >> 4;

  float4v acc[8][4];
#pragma unroll
  for (int i = 0; i < 8; ++i)
#pragma unroll
    for (int j = 0; j < 4; ++j) acc[i][j] = (float4v){0.f, 0.f, 0.f, 0.f};

  // staging: lane l -> row group rg = l>>3, 16B chunk c8 = l&7; pre-swizzled source.
  const int rg = l >> 3;
  const int c8 = l & 7;
  const int ksw = (c8 ^ rg) << 3;  // swizzled k-offset (elements)

#define STAGE(kt_, buf_)                                                        \
  {                                                                             \
    const int k0_ = (kt_) << 6;                                                 \
    _Pragma("unroll") for (int i_ = 0; i_ < 4; ++i_) {                          \
      const int trow_ = (i_ << 6) + (w << 3) + rg; /* trow&7 == rg */           \
      const size_t ga_ = (size_t)(brow + trow_) * DD + k0_ + ksw;               \
      const size_t gb_ = (size_t)(bcol + trow_) * DD + k0_ + ksw;               \
      const int lofs_ = ((i_ << 3) + w) << 9;                                   \
      if constexpr (BF16WS) {                                                   \
        __builtin_amdgcn_global_load_lds(                                       \
            (const __attribute__((address_space(1))) void*)(Abf + ga_),         \
            (__attribute__((address_space(3))) void*)(&As[buf_][lofs_]), 16, 0, \
            0);                                                                 \
        __builtin_amdgcn_global_load_lds(                                       \
            (const __attribute__((address_space(1))) void*)(Bbf + gb_),         \
            (__attribute__((address_space(3))) void*)(&Bs[buf_][lofs_]), 16, 0, \
            0);                                                                 \
      } else {                                                                  \
        const float4v* pa_ = (const float4v*)(A32 + ga_);                       \
        const float4v* pb_ = (const float4v*)(B32 + gb_);                       \
        *(short8*)((char*)&As[buf_][lofs_] + l * 16) = pack8(pa_[0], pa_[1]);   \
        *(short8*)((char*)&Bs[buf_][lofs_] + l * 16) = pack8(pb_[0], pb_[1]);   \
      }                                                                         \
    }                                                                           \
  }

  STAGE(0, 0);
  __syncthreads();  // drains vmcnt(0): buf0 ready
  int cur = 0;
  for (int kt = 0; kt < 4; ++kt) {
    if (kt < 3) STAGE(kt + 1, cur ^ 1);  // async prefetch, in flight during compute
#pragma unroll
    for (int kk = 0; kk < 2; ++kk) {
      const int kb = (kk << 6) + (quad << 4);
      const int sw = (col16 & 7) << 4;
      short8 af[8], bfv[4];
#pragma unroll
      for (int mi = 0; mi < 8; ++mi) {
        const int row = (wr << 7) + (mi << 4) + col16;
        af[mi] = *(const short8*)((const char*)&As[cur][0] + row * 128 + (kb ^ sw));
      }
#pragma unroll
      for (int ni = 0; ni < 4; ++ni) {
        const int row = (wc << 6) + (ni << 4) + col16;
        bfv[ni] = *(const short8*)((const char*)&Bs[cur][0] + row * 128 + (kb ^ sw));
      }
#pragma unroll
      for (int mi = 0; mi < 8; ++mi)
#pragma unroll
        for (int ni = 0; ni < 4; ++ni)
          acc[mi][ni] = __builtin_amdgcn_mfma_f32_16x16x32_bf16(
              af[mi], bfv[ni], acc[mi][ni], 0, 0, 0);
    }
    if (kt < 3) {
      __syncthreads();  // drains: cur's ds_reads (lgkm) + next buf's stage (vmcnt)
      cur ^= 1;
    }
  }
#undef STAGE

  // ---- fused epilogue, base-2: softplus(t) = ln2*(max(u,0)+log2(1+2^-|u|)), u=t*log2e
  const float s2 = (*scale_p) * LOG2E;
  const float b2 = (*bias_p) * LOG2E;
  float st = 0.f, sp = 0.f;
  int pc = 0;

  int lbv[4];
#pragma unroll
  for (int ni = 0; ni < 4; ++ni) lbv[ni] = lb[bcol + (wc << 6) + (ni << 4) + col16];

#pragma unroll
  for (int mi = 0; mi < 8; ++mi) {
#pragma unroll
    for (int r = 0; r < 4; ++r) {
      const int grow = brow + (wr << 7) + (mi << 4) + (quad << 2) + r;
      const int lav = la[grow];
#pragma unroll
      for (int ni = 0; ni < 4; ++ni) {
        const float v = fmaf(s2, acc[mi][ni][r], b2);  // logit*log2e
        const bool m = (lav == lbv[ni]);
        const float u = m ? -v : v;  // (-labels*logits)*log2e
        const float x = fmaxf(u, 0.f) + fast_log2(1.f + fast_exp2(-fabsf(u)));
        st += x;
        if (m) { sp += x; ++pc; }  // rare (p ~ 1/4096)
      }
    }
  }

  // deterministic per-block partials
#pragma unroll
  for (int off = 32; off > 0; off >>= 1) {
    st += __shfl_down(st, off);
    sp += __shfl_down(sp, off);
    pc += __shfl_down(pc, off);
  }
  if (l == 0) { redp[w] = sp; redn[w] = st; redc[w] = (unsigned)pc; }
  __syncthreads();
  if (tid == 0) {
    float tp = 0.f, tt = 0.f;
    unsigned tc = 0;
#pragma unroll
    for (int i = 0; i < 8; ++i) { tp += redp[i]; tt += redn[i]; tc += redc[i]; }
    pos_part[blockIdx.x] = LN2 * tp;
    neg_part[blockIdx.x] = LN2 * (tt - tp);
    cnt_part[blockIdx.x] = tc;
  }
}

__global__ __launch_bounds__(512, 2) void gemm_sigloss_bf16ws(
    const unsigned short* __restrict__ Abf, const unsigned short* __restrict__ Bbf,
    const int* __restrict__ la, const int* __restrict__ lb,
    const float* __restrict__ scale_p, const float* __restrict__ bias_p,
    float* __restrict__ pos_part, float* __restrict__ neg_part,
    unsigned* __restrict__ cnt_part) {
  gemm_sigloss_body<true>(Abf, Bbf, nullptr, nullptr, la, lb, scale_p, bias_p,
                          pos_part, neg_part, cnt_part);
}

__global__ __launch_bounds__(512, 2) void gemm_sigloss_f32(
    const float* __restrict__ A32, const float* __restrict__ B32,
    const int* __restrict__ la, const int* __restrict__ lb,
    const float* __restrict__ scale_p, const float* __restrict__ bias_p,
    float* __restrict__ pos_part, float* __restrict__ neg_part,
    unsigned* __restrict__ cnt_part) {
  gemm_sigloss_body<false>(nullptr, nullptr, A32, B32, la, lb, scale_p, bias_p,
                           pos_part, neg_part, cnt_part);
}

__global__ __launch_bounds__(256) void finalize_loss(
    const float* __restrict__ pos_part, const float* __restrict__ neg_part,
    const unsigned* __restrict__ cnt_part, float* __restrict__ out) {
  __shared__ float rp[4], rn[4];
  __shared__ unsigned rc[4];
  const int w = threadIdx.x >> 6;
  const int l = threadIdx.x & 63;
  float ps = 0.f, ns = 0.f;
  int pc = 0;
  for (int i = threadIdx.x; i < NPART; i += 256) {
    ps += pos_part[i];
    ns += neg_part[i];
    pc += (int)cnt_part[i];
  }
#pragma unroll
  for (int off = 32; off > 0; off >>= 1) {
    ps += __shfl_down(ps, off);
    ns += __shfl_down(ns, off);
    pc += __shfl_down(pc, off);
  }
  if (l == 0) { rp[w] = ps; rn[w] = ns; rc[w] = (unsigned)pc; }
  __syncthreads();
  if (threadIdx.x == 0) {
    double tp = (double)rp[0] + rp[1] + rp[2] + rp[3];
    double tn = (double)rn[0] + rn[1] + rn[2] + rn[3];
    long long tc = (long long)rc[0] + rc[1] + rc[2] + rc[3];
    double num_pos = (double)(tc > 1 ? tc : 1);
    long long negc = (long long)NN * MM - tc;
    double num_neg = (double)(negc > 1 ? negc : 1);
    out[0] = (float)(tp / num_pos + tn / num_neg * (double)(NN - 1));
  }
}

extern "C" void kernel_launch(void* const* d_in, const int* in_sizes, int n_in,
                              void* d_out, int out_size, void* d_ws, size_t ws_size,
                              hipStream_t stream) {
  const float* A32 = (const float*)d_in[0];
  const float* B32 = (const float*)d_in[1];
  const int* la = (const int*)d_in[2];
  const int* lb = (const int*)d_in[3];
  const float* scale_p = (const float*)d_in[4];
  const float* bias_p = (const float*)d_in[5];
  float* out = (float*)d_out;

  char* ws = (char*)d_ws;
  float* pos_part = (float*)ws;                       // 1024 f32
  float* neg_part = pos_part + NPART;                 // 1024 f32
  unsigned* cnt_part = (unsigned*)(neg_part + NPART); // 1024 u32
  unsigned short* Abf = (unsigned short*)(ws + 65536);
  unsigned short* Bbf = Abf + (size_t)NN * DD;

  const size_t need = 65536 + 2ull * (size_t)NN * DD * 2;
  const bool usebf = (ws_size >= need);

  if (usebf) {
    convert_both<<<2048, 256, 0, stream>>>(A32, B32, Abf, Bbf);
    gemm_sigloss_bf16ws<<<NPART, 512, 0, stream>>>(Abf, Bbf, la, lb, scale_p,
                                                   bias_p, pos_part, neg_part,
                                                   cnt_part);
  } else {
    gemm_sigloss_f32<<<NPART, 512, 0, stream>>>(A32, B32, la, lb, scale_p,
                                                bias_p, pos_part, neg_part,
                                                cnt_part);
  }
  finalize_loss<<<1, 256, 0, stream>>>(pos_part, neg_part, cnt_part, out);
}

// Round 5
// 75.257 us; speedup vs baseline: 2.6739x; 1.0264x over previous
//
#include <hip/hip_runtime.h>
#include <hip/hip_bf16.h>
#include <stdint.h>
#include <math.h>

#define NN 8192
#define MM 8192
#define DD 256
#define BT 256
#define NPART ((NN / BT) * (MM / BT))  // 1024 blocks
#define LOG2E 1.44269504088896340736f
#define LN2 0.69314718055994530942f

typedef __attribute__((ext_vector_type(8))) short short8;
typedef __attribute__((ext_vector_type(4))) float float4v;
typedef __attribute__((ext_vector_type(2))) unsigned uint2v;

__device__ __forceinline__ unsigned cvt_pk_bf16(float lo, float hi) {
  unsigned r;
  asm("v_cvt_pk_bf16_f32 %0, %1, %2" : "=v"(r) : "v"(lo), "v"(hi));
  return r;
}
__device__ __forceinline__ float fast_exp2(float x) {
  float r;
  asm("v_exp_f32 %0, %1" : "=v"(r) : "v"(x));
  return r;
}
__device__ __forceinline__ float fast_log2(float x) {
  float r;
  asm("v_log_f32 %0, %1" : "=v"(r) : "v"(x));
  return r;
}

__global__ void convert_both(const float* __restrict__ A32,
                             const float* __restrict__ B32,
                             unsigned short* __restrict__ Abf,
                             unsigned short* __restrict__ Bbf) {
  const int n4 = NN * DD / 4;
  const int stride = gridDim.x * blockDim.x;
  for (int idx = blockIdx.x * blockDim.x + threadIdx.x; idx < 2 * n4;
       idx += stride) {
    const bool isA = idx < n4;
    const int j = isA ? idx : idx - n4;
    float4v x = isA ? ((const float4v*)A32)[j] : ((const float4v*)B32)[j];
    uint2v o;
    o[0] = cvt_pk_bf16(x[0], x[1]);
    o[1] = cvt_pk_bf16(x[2], x[3]);
    if (isA) ((uint2v*)Abf)[j] = o;
    else     ((uint2v*)Bbf)[j] = o;
  }
}

__device__ __forceinline__ short8 pack8(float4v a0, float4v a1) {
  union { short8 s; unsigned u[4]; } r;
  r.u[0] = cvt_pk_bf16(a0[0], a0[1]);
  r.u[1] = cvt_pk_bf16(a0[2], a0[3]);
  r.u[2] = cvt_pk_bf16(a1[0], a1[1]);
  r.u[3] = cvt_pk_bf16(a1[2], a1[3]);
  return r.s;
}

// ===================== 8-phase pipelined bf16 kernel =====================
// 256x256 tile, BK=64, 8 waves (2Mx4N), per-wave 128x64 via 8x4 mfma 16x16x32.
// LDS [2][256][64] bf16 per operand, XOR swizzle phys_kbyte = kbyte^((row&7)<<4),
// staged via pre-swizzled GLOBAL source + linear LDS dest (global_load_lds w=16).
// K-loop: 4 K-tiles x 4 phases; phase = {ds_read quadrant | stage-issue,
// s_barrier, lgkmcnt(0), setprio(1), 16 MFMA, setprio(0), [vmcnt], s_barrier}.
// vmcnt never drained mid-tile; T2/T3 issued a full tile before their wait.
__global__ __launch_bounds__(512, 2) void gemm_sigloss_bf16ws(
    const unsigned short* __restrict__ Abf, const unsigned short* __restrict__ Bbf,
    const int* __restrict__ la, const int* __restrict__ lb,
    const float* __restrict__ scale_p, const float* __restrict__ bias_p,
    float* __restrict__ pos_part, float* __restrict__ neg_part,
    unsigned* __restrict__ cnt_part) {
  __shared__ unsigned short As[2][BT * 64];
  __shared__ unsigned short Bs[2][BT * 64];
  __shared__ float redp[8], redn[8];
  __shared__ unsigned redc[8];

  const int tid = threadIdx.x;
  const int w = tid >> 6;
  const int l = tid & 63;
  const int sb = ((blockIdx.x & 7) << 7) | (blockIdx.x >> 3);  // bijective XCD swz
  const int brow = (sb >> 5) << 8;
  const int bcol = (sb & 31) << 8;
  const int wr = w >> 2;
  const int wc = w & 3;
  const int col16 = l & 15;
  const int quad = l >> 4;

  float4v acc[8][4];
#pragma unroll
  for (int i = 0; i < 8; ++i)
#pragma unroll
    for (int j = 0; j < 4; ++j) acc[i][j] = (float4v){0.f, 0.f, 0.f, 0.f};

  // staging geometry (pre-swizzled global source)
  const int rg = l >> 3;
  const int c8 = l & 7;
  const int ksw = (c8 ^ rg) << 3;
  const unsigned short* aP[4];
  const unsigned short* bP[4];
#pragma unroll
  for (int i = 0; i < 4; ++i) {
    const int trow = (i << 6) + (w << 3) + rg;  // trow&7 == rg
    aP[i] = Abf + (size_t)(brow + trow) * DD + ksw;
    bP[i] = Bbf + (size_t)(bcol + trow) * DD + ksw;
  }

#define STAGE(kt_, buf_)                                                      \
  {                                                                           \
    _Pragma("unroll") for (int i_ = 0; i_ < 4; ++i_) {                        \
      const int lofs_ = ((i_ << 3) + w) << 9;                                 \
      __builtin_amdgcn_global_load_lds(                                       \
          (const __attribute__((address_space(1))) void*)(aP[i_] +            \
                                                          ((kt_) << 6)),      \
          (__attribute__((address_space(3))) void*)(&As[buf_][lofs_]), 16, 0, \
          0);                                                                 \
      __builtin_amdgcn_global_load_lds(                                       \
          (const __attribute__((address_space(1))) void*)(bP[i_] +            \
                                                          ((kt_) << 6)),      \
          (__attribute__((address_space(3))) void*)(&Bs[buf_][lofs_]), 16, 0, \
          0);                                                                 \
    }                                                                         \
  }

  short8 bf[4];
  const int sw = (col16 & 7) << 4;

#define PHASE(buf_, kk_, mh_, STAGE_STMT, VM_STMT)                             \
  {                                                                            \
    short8 af[4];                                                              \
    const int kb_ = ((kk_) << 6) + (quad << 4);                                \
    _Pragma("unroll") for (int i_ = 0; i_ < 4; ++i_) {                         \
      const int row_ = (wr << 7) + ((((mh_) << 2) | i_) << 4) + col16;         \
      af[i_] = *(const short8*)((const char*)&As[buf_][0] + row_ * 128 +       \
                                (kb_ ^ sw));                                   \
    }                                                                          \
    if ((mh_) == 0) {                                                          \
      _Pragma("unroll") for (int i_ = 0; i_ < 4; ++i_) {                       \
        const int row_ = (wc << 6) + (i_ << 4) + col16;                        \
        bf[i_] = *(const short8*)((const char*)&Bs[buf_][0] + row_ * 128 +     \
                                  (kb_ ^ sw));                                 \
      }                                                                        \
    }                                                                          \
    STAGE_STMT;                                                                \
    __builtin_amdgcn_s_barrier();                                              \
    asm volatile("s_waitcnt lgkmcnt(0)" ::: "memory");                         \
    __builtin_amdgcn_sched_barrier(0);                                         \
    __builtin_amdgcn_s_setprio(1);                                             \
    _Pragma("unroll") for (int mi_ = 0; mi_ < 4; ++mi_)                        \
        _Pragma("unroll") for (int ni_ = 0; ni_ < 4; ++ni_)                    \
            acc[((mh_) << 2) | mi_][ni_] =                                     \
                __builtin_amdgcn_mfma_f32_16x16x32_bf16(                       \
                    af[mi_], bf[ni_], acc[((mh_) << 2) | mi_][ni_], 0, 0, 0);  \
    __builtin_amdgcn_s_setprio(0);                                             \
    __builtin_amdgcn_sched_barrier(0);                                         \
    VM_STMT;                                                                   \
    __builtin_amdgcn_s_barrier();                                              \
  }

#define VWAIT0 asm volatile("s_waitcnt vmcnt(0)" ::: "memory")
#define NOSTMT ((void)0)

  // prologue: T0->b0, T1->b1 (16 loads); wait oldest 8 (T0), publish
  STAGE(0, 0);
  STAGE(1, 1);
  asm volatile("s_waitcnt vmcnt(8)" ::: "memory");
  __builtin_amdgcn_s_barrier();

  // tile 0 (b0); end waits T1 (issued in prologue, long done)
  PHASE(0, 0, 0, NOSTMT, NOSTMT);
  PHASE(0, 0, 1, NOSTMT, NOSTMT);
  PHASE(0, 1, 0, NOSTMT, NOSTMT);
  PHASE(0, 1, 1, NOSTMT, VWAIT0);
  // tile 1 (b1); b0 free now -> stage T2 at p0; end waits T2 (4 phases of cover)
  PHASE(1, 0, 0, STAGE(2, 0), NOSTMT);
  PHASE(1, 0, 1, NOSTMT, NOSTMT);
  PHASE(1, 1, 0, NOSTMT, NOSTMT);
  PHASE(1, 1, 1, NOSTMT, VWAIT0);
  // tile 2 (b0); stage T3->b1 at p0
  PHASE(0, 0, 0, STAGE(3, 1), NOSTMT);
  PHASE(0, 0, 1, NOSTMT, NOSTMT);
  PHASE(0, 1, 0, NOSTMT, NOSTMT);
  PHASE(0, 1, 1, NOSTMT, VWAIT0);
  // tile 3 (b1)
  PHASE(1, 0, 0, NOSTMT, NOSTMT);
  PHASE(1, 0, 1, NOSTMT, NOSTMT);
  PHASE(1, 1, 0, NOSTMT, NOSTMT);
  PHASE(1, 1, 1, NOSTMT, NOSTMT);

#undef PHASE
#undef STAGE
#undef VWAIT0
#undef NOSTMT

  // ---- fused epilogue, base-2 softplus ----
  const float s2 = (*scale_p) * LOG2E;
  const float b2 = (*bias_p) * LOG2E;
  float st = 0.f, sp = 0.f;
  int pc = 0;

  int lbv[4];
#pragma unroll
  for (int ni = 0; ni < 4; ++ni) lbv[ni] = lb[bcol + (wc << 6) + (ni << 4) + col16];

#pragma unroll
  for (int mi = 0; mi < 8; ++mi) {
#pragma unroll
    for (int r = 0; r < 4; ++r) {
      const int grow = brow + (wr << 7) + (mi << 4) + (quad << 2) + r;
      const int lav = la[grow];
#pragma unroll
      for (int ni = 0; ni < 4; ++ni) {
        const float v = fmaf(s2, acc[mi][ni][r], b2);
        const bool m = (lav == lbv[ni]);
        const float u = m ? -v : v;
        const float x = fmaxf(u, 0.f) + fast_log2(1.f + fast_exp2(-fabsf(u)));
        st += x;
        if (m) { sp += x; ++pc; }
      }
    }
  }

#pragma unroll
  for (int off = 32; off > 0; off >>= 1) {
    st += __shfl_down(st, off);
    sp += __shfl_down(sp, off);
    pc += __shfl_down(pc, off);
  }
  if (l == 0) { redp[w] = sp; redn[w] = st; redc[w] = (unsigned)pc; }
  __syncthreads();
  if (tid == 0) {
    float tp = 0.f, tt = 0.f;
    unsigned tc = 0;
#pragma unroll
    for (int i = 0; i < 8; ++i) { tp += redp[i]; tt += redn[i]; tc += redc[i]; }
    pos_part[blockIdx.x] = LN2 * tp;
    neg_part[blockIdx.x] = LN2 * (tt - tp);
    cnt_part[blockIdx.x] = tc;
  }
}

// ===================== safe f32 fallback (simple 2-phase) =====================
__global__ __launch_bounds__(512, 2) void gemm_sigloss_f32(
    const float* __restrict__ A32, const float* __restrict__ B32,
    const int* __restrict__ la, const int* __restrict__ lb,
    const float* __restrict__ scale_p, const float* __restrict__ bias_p,
    float* __restrict__ pos_part, float* __restrict__ neg_part,
    unsigned* __restrict__ cnt_part) {
  __shared__ unsigned short As[2][BT * 64];
  __shared__ unsigned short Bs[2][BT * 64];
  __shared__ float redp[8], redn[8];
  __shared__ unsigned redc[8];

  const int tid = threadIdx.x;
  const int w = tid >> 6;
  const int l = tid & 63;
  const int sb = ((blockIdx.x & 7) << 7) | (blockIdx.x >> 3);
  const int brow = (sb >> 5) << 8;
  const int bcol = (sb & 31) << 8;
  const int wr = w >> 2;
  const int wc = w & 3;
  const int col16 = l & 15;
  const int quad = l >> 4;

  float4v acc[8][4];
#pragma unroll
  for (int i = 0; i < 8; ++i)
#pragma unroll
    for (int j = 0; j < 4; ++j) acc[i][j] = (float4v){0.f, 0.f, 0.f, 0.f};

  const int rg = l >> 3;
  const int c8 = l & 7;
  const int ksw = (c8 ^ rg) << 3;

  int cur = 0;
  for (int kt = 0; kt < 4; ++kt) {
    const int k0 = kt << 6;
#pragma unroll
    for (int i = 0; i < 4; ++i) {
      const int trow = (i << 6) + (w << 3) + rg;
      const float4v* pa = (const float4v*)(A32 + (size_t)(brow + trow) * DD + k0 + ksw);
      const float4v* pb = (const float4v*)(B32 + (size_t)(bcol + trow) * DD + k0 + ksw);
      const int lofs = ((i << 3) + w) << 9;
      *(short8*)((char*)&As[cur][lofs] + l * 16) = pack8(pa[0], pa[1]);
      *(short8*)((char*)&Bs[cur][lofs] + l * 16) = pack8(pb[0], pb[1]);
    }
    __syncthreads();
#pragma unroll
    for (int kk = 0; kk < 2; ++kk) {
      const int kb = (kk << 6) + (quad << 4);
      const int sw = (col16 & 7) << 4;
      short8 af[8], bfv[4];
#pragma unroll
      for (int mi = 0; mi < 8; ++mi) {
        const int row = (wr << 7) + (mi << 4) + col16;
        af[mi] = *(const short8*)((const char*)&As[cur][0] + row * 128 + (kb ^ sw));
      }
#pragma unroll
      for (int ni = 0; ni < 4; ++ni) {
        const int row = (wc << 6) + (ni << 4) + col16;
        bfv[ni] = *(const short8*)((const char*)&Bs[cur][0] + row * 128 + (kb ^ sw));
      }
#pragma unroll
      for (int mi = 0; mi < 8; ++mi)
#pragma unroll
        for (int ni = 0; ni < 4; ++ni)
          acc[mi][ni] = __builtin_amdgcn_mfma_f32_16x16x32_bf16(
              af[mi], bfv[ni], acc[mi][ni], 0, 0, 0);
    }
    __syncthreads();
    cur ^= 1;
  }

  const float s2 = (*scale_p) * LOG2E;
  const float b2 = (*bias_p) * LOG2E;
  float st = 0.f, sp = 0.f;
  int pc = 0;
  int lbv[4];
#pragma unroll
  for (int ni = 0; ni < 4; ++ni) lbv[ni] = lb[bcol + (wc << 6) + (ni << 4) + col16];
#pragma unroll
  for (int mi = 0; mi < 8; ++mi) {
#pragma unroll
    for (int r = 0; r < 4; ++r) {
      const int grow = brow + (wr << 7) + (mi << 4) + (quad << 2) + r;
      const int lav = la[grow];
#pragma unroll
      for (int ni = 0; ni < 4; ++ni) {
        const float v = fmaf(s2, acc[mi][ni][r], b2);
        const bool m = (lav == lbv[ni]);
        const float u = m ? -v : v;
        const float x = fmaxf(u, 0.f) + fast_log2(1.f + fast_exp2(-fabsf(u)));
        st += x;
        if (m) { sp += x; ++pc; }
      }
    }
  }
#pragma unroll
  for (int off = 32; off > 0; off >>= 1) {
    st += __shfl_down(st, off);
    sp += __shfl_down(sp, off);
    pc += __shfl_down(pc, off);
  }
  if (l == 0) { redp[w] = sp; redn[w] = st; redc[w] = (unsigned)pc; }
  __syncthreads();
  if (tid == 0) {
    float tp = 0.f, tt = 0.f;
    unsigned tc = 0;
#pragma unroll
    for (int i = 0; i < 8; ++i) { tp += redp[i]; tt += redn[i]; tc += redc[i]; }
    pos_part[blockIdx.x] = LN2 * tp;
    neg_part[blockIdx.x] = LN2 * (tt - tp);
    cnt_part[blockIdx.x] = tc;
  }
}

__global__ __launch_bounds__(256) void finalize_loss(
    const float* __restrict__ pos_part, const float* __restrict__ neg_part,
    const unsigned* __restrict__ cnt_part, float* __restrict__ out) {
  __shared__ float rp[4], rn[4];
  __shared__ unsigned rc[4];
  const int w = threadIdx.x >> 6;
  const int l = threadIdx.x & 63;
  float ps = 0.f, ns = 0.f;
  int pc = 0;
  for (int i = threadIdx.x; i < NPART; i += 256) {
    ps += pos_part[i];
    ns += neg_part[i];
    pc += (int)cnt_part[i];
  }
#pragma unroll
  for (int off = 32; off > 0; off >>= 1) {
    ps += __shfl_down(ps, off);
    ns += __shfl_down(ns, off);
    pc += __shfl_down(pc, off);
  }
  if (l == 0) { rp[w] = ps; rn[w] = ns; rc[w] = (unsigned)pc; }
  __syncthreads();
  if (threadIdx.x == 0) {
    double tp = (double)rp[0] + rp[1] + rp[2] + rp[3];
    double tn = (double)rn[0] + rn[1] + rn[2] + rn[3];
    long long tc = (long long)rc[0] + rc[1] + rc[2] + rc[3];
    double num_pos = (double)(tc > 1 ? tc : 1);
    long long negc = (long long)NN * MM - tc;
    double num_neg = (double)(negc > 1 ? negc : 1);
    out[0] = (float)(tp / num_pos + tn / num_neg * (double)(NN - 1));
  }
}

extern "C" void kernel_launch(void* const* d_in, const int* in_sizes, int n_in,
                              void* d_out, int out_size, void* d_ws, size_t ws_size,
                              hipStream_t stream) {
  const float* A32 = (const float*)d_in[0];
  const float* B32 = (const float*)d_in[1];
  const int* la = (const int*)d_in[2];
  const int* lb = (const int*)d_in[3];
  const float* scale_p = (const float*)d_in[4];
  const float* bias_p = (const float*)d_in[5];
  float* out = (float*)d_out;

  char* ws = (char*)d_ws;
  float* pos_part = (float*)ws;
  float* neg_part = pos_part + NPART;
  unsigned* cnt_part = (unsigned*)(neg_part + NPART);
  unsigned short* Abf = (unsigned short*)(ws + 65536);
  unsigned short* Bbf = Abf + (size_t)NN * DD;

  const size_t need = 65536 + 2ull * (size_t)NN * DD * 2;
  const bool usebf = (ws_size >= need);

  if (usebf) {
    convert_both<<<2048, 256, 0, stream>>>(A32, B32, Abf, Bbf);
    gemm_sigloss_bf16ws<<<NPART, 512, 0, stream>>>(Abf, Bbf, la, lb, scale_p,
                                                   bias_p, pos_part, neg_part,
                                                   cnt_part);
  } else {
    gemm_sigloss_f32<<<NPART, 512, 0, stream>>>(A32, B32, la, lb, scale_p,
                                                bias_p, pos_part, neg_part,
                                                cnt_part);
  }
  finalize_loss<<<1, 256, 0, stream>>>(pos_part, neg_part, cnt_part, out);
}

// Round 6
// 62.595 us; speedup vs baseline: 3.2148x; 1.2023x over previous
//
#include <hip/hip_runtime.h>
#include <hip/hip_bf16.h>
#include <stdint.h>
#include <math.h>

#define NN 8192
#define MM 8192
#define DD 256
#define NPART ((NN / 128) * (MM / 128))  // 4096 blocks
#define LOG2E 1.44269504088896340736f
#define LN2 0.69314718055994530942f

typedef __attribute__((ext_vector_type(8))) short short8;
typedef __attribute__((ext_vector_type(4))) float float4v;
typedef __attribute__((ext_vector_type(2))) unsigned uint2v;

__device__ __forceinline__ unsigned cvt_pk_bf16(float lo, float hi) {
  unsigned r;
  asm("v_cvt_pk_bf16_f32 %0, %1, %2" : "=v"(r) : "v"(lo), "v"(hi));
  return r;
}

__global__ void convert_both(const float* __restrict__ A32,
                             const float* __restrict__ B32,
                             unsigned short* __restrict__ Abf,
                             unsigned short* __restrict__ Bbf) {
  const int n4 = NN * DD / 4;
  const int stride = gridDim.x * blockDim.x;
  for (int idx = blockIdx.x * blockDim.x + threadIdx.x; idx < 2 * n4;
       idx += stride) {
    const bool isA = idx < n4;
    const int j = isA ? idx : idx - n4;
    float4v x = isA ? ((const float4v*)A32)[j] : ((const float4v*)B32)[j];
    uint2v o;
    o[0] = cvt_pk_bf16(x[0], x[1]);
    o[1] = cvt_pk_bf16(x[2], x[3]);
    if (isA) ((uint2v*)Abf)[j] = o;
    else     ((uint2v*)Bbf)[j] = o;
  }
}

__device__ __forceinline__ short8 pack8(float4v a0, float4v a1) {
  union { short8 s; unsigned u[4]; } r;
  r.u[0] = cvt_pk_bf16(a0[0], a0[1]);
  r.u[1] = cvt_pk_bf16(a0[2], a0[3]);
  r.u[2] = cvt_pk_bf16(a1[0], a1[1]);
  r.u[3] = cvt_pk_bf16(a1[2], a1[3]);
  return r.s;
}

// 128x128 tile, BK=64, 4 waves (2x2), each wave 64x64 via 4x4 mfma_f32_16x16x32_bf16.
// Single-buffered LDS (32KB) -> 3 blocks/CU co-resident (144 regs/wave): block n's
// epilogue VALU overlaps block n+1's staging stalls (TLP, not schedule depth).
// LDS rows 128B, XOR swizzle phys_kbyte = kbyte ^ ((row&7)<<4), staged via
// pre-swizzled GLOBAL source + linear LDS dest (global_load_lds width 16).
template <bool BF16WS>
__device__ __forceinline__ void gemm_sigloss_body(
    const unsigned short* __restrict__ Abf, const unsigned short* __restrict__ Bbf,
    const float* __restrict__ A32, const float* __restrict__ B32,
    const int* __restrict__ la, const int* __restrict__ lb,
    const float* __restrict__ scale_p, const float* __restrict__ bias_p,
    float* __restrict__ pos_part, float* __restrict__ neg_part,
    unsigned* __restrict__ cnt_part) {
  __shared__ unsigned short As[128 * 64];
  __shared__ unsigned short Bs[128 * 64];
  __shared__ float redp[4], redn[4];
  __shared__ unsigned redc[4];

  const int tid = threadIdx.x;
  const int w = tid >> 6;
  const int l = tid & 63;
  // bijective XCD swizzle: 4096 % 8 == 0
  const int bid = ((blockIdx.x & 7) << 9) + (blockIdx.x >> 3);
  const int brow = (bid >> 6) << 7;
  const int bcol = (bid & 63) << 7;
  const int wrow = (w >> 1) << 6;
  const int wcol = (w & 1) << 6;
  const int col16 = l & 15;
  const int quad = l >> 4;

  float4v acc[4][4];
#pragma unroll
  for (int i = 0; i < 4; ++i)
#pragma unroll
    for (int j = 0; j < 4; ++j) acc[i][j] = (float4v){0.f, 0.f, 0.f, 0.f};

  // staging: lane l -> row group rg = l>>3, 16B chunk c8 = l&7 (pre-swizzled src)
  const int rg = l >> 3;
  const int c8 = l & 7;
  const int ksw = (c8 ^ rg) << 3;

  for (int kt = 0; kt < DD / 64; ++kt) {
    const int k0 = kt << 6;
#pragma unroll
    for (int i = 0; i < 4; ++i) {
      const int trow = (w << 5) + (i << 3) + rg;  // tile row; trow&7 == rg
      const size_t ga = (size_t)(brow + trow) * DD + k0 + ksw;
      const size_t gb = (size_t)(bcol + trow) * DD + k0 + ksw;
      const int lofs = ((w << 2) + i) << 9;
      if constexpr (BF16WS) {
        __builtin_amdgcn_global_load_lds(
            (const __attribute__((address_space(1))) void*)(Abf + ga),
            (__attribute__((address_space(3))) void*)(&As[lofs]), 16, 0, 0);
        __builtin_amdgcn_global_load_lds(
            (const __attribute__((address_space(1))) void*)(Bbf + gb),
            (__attribute__((address_space(3))) void*)(&Bs[lofs]), 16, 0, 0);
      } else {
        const float4v* pa = (const float4v*)(A32 + ga);
        const float4v* pb = (const float4v*)(B32 + gb);
        *(short8*)((char*)As + (size_t)lofs * 2 + (size_t)l * 16) = pack8(pa[0], pa[1]);
        *(short8*)((char*)Bs + (size_t)lofs * 2 + (size_t)l * 16) = pack8(pb[0], pb[1]);
      }
    }
    __syncthreads();
#pragma unroll
    for (int kk = 0; kk < 2; ++kk) {
      const int kb = (kk << 6) + (quad << 4);
      const int sw = (col16 & 7) << 4;
      short8 af[4], bfv[4];
#pragma unroll
      for (int mi = 0; mi < 4; ++mi) {
        const int row = wrow + (mi << 4) + col16;
        af[mi] = *(const short8*)((const char*)As + row * 128 + (kb ^ sw));
      }
#pragma unroll
      for (int ni = 0; ni < 4; ++ni) {
        const int row = wcol + (ni << 4) + col16;
        bfv[ni] = *(const short8*)((const char*)Bs + row * 128 + (kb ^ sw));
      }
#pragma unroll
      for (int mi = 0; mi < 4; ++mi)
#pragma unroll
        for (int ni = 0; ni < 4; ++ni)
          acc[mi][ni] = __builtin_amdgcn_mfma_f32_16x16x32_bf16(
              af[mi], bfv[ni], acc[mi][ni], 0, 0, 0);
    }
    __syncthreads();
  }

  // ---- slim fused epilogue, base-2 softplus: 7 VALU + 2 TRANS per elem ----
  // softplus(t) = ln2*(max(u,0) + log2(1+2^-|u|)), u = t*log2e
  const float s2 = (*scale_p) * LOG2E;
  const float b2 = (*bias_p) * LOG2E;
  float st = 0.f, sp = 0.f;
  int pc = 0;

  int lbv[4];
#pragma unroll
  for (int ni = 0; ni < 4; ++ni) lbv[ni] = lb[bcol + wcol + (ni << 4) + col16];

#pragma unroll
  for (int mi = 0; mi < 4; ++mi) {
#pragma unroll
    for (int r = 0; r < 4; ++r) {
      const int grow = brow + wrow + (mi << 4) + (quad << 2) + r;
      const int lav = la[grow];
#pragma unroll
      for (int ni = 0; ni < 4; ++ni) {
        const float v = fmaf(s2, acc[mi][ni][r], b2);  // logit*log2e
        const bool m = (lav == lbv[ni]);
        const float u = m ? -v : v;  // cndmask w/ neg modifier
        const float e = __builtin_amdgcn_exp2f(-fabsf(u));  // mods fold
        const float x = fmaxf(u, 0.f) + __builtin_amdgcn_logf(1.f + e);
        st += x;
        if (__builtin_expect(__any(m), 0)) {  // rare: P ~ 1.6% per wave-iter
          if (m) { sp += x; ++pc; }
        }
      }
    }
  }

  // deterministic per-block partials
#pragma unroll
  for (int off = 32; off > 0; off >>= 1) {
    st += __shfl_down(st, off);
    sp += __shfl_down(sp, off);
    pc += __shfl_down(pc, off);
  }
  if (l == 0) { redp[w] = sp; redn[w] = st; redc[w] = (unsigned)pc; }
  __syncthreads();
  if (tid == 0) {
    const float tp = redp[0] + redp[1] + redp[2] + redp[3];
    const float tt = redn[0] + redn[1] + redn[2] + redn[3];
    pos_part[bid] = LN2 * tp;
    neg_part[bid] = LN2 * (tt - tp);
    cnt_part[bid] = redc[0] + redc[1] + redc[2] + redc[3];
  }
}

__global__ __launch_bounds__(256, 3) void gemm_sigloss_bf16ws(
    const unsigned short* __restrict__ Abf, const unsigned short* __restrict__ Bbf,
    const int* __restrict__ la, const int* __restrict__ lb,
    const float* __restrict__ scale_p, const float* __restrict__ bias_p,
    float* __restrict__ pos_part, float* __restrict__ neg_part,
    unsigned* __restrict__ cnt_part) {
  gemm_sigloss_body<true>(Abf, Bbf, nullptr, nullptr, la, lb, scale_p, bias_p,
                          pos_part, neg_part, cnt_part);
}

__global__ __launch_bounds__(256, 3) void gemm_sigloss_f32(
    const float* __restrict__ A32, const float* __restrict__ B32,
    const int* __restrict__ la, const int* __restrict__ lb,
    const float* __restrict__ scale_p, const float* __restrict__ bias_p,
    float* __restrict__ pos_part, float* __restrict__ neg_part,
    unsigned* __restrict__ cnt_part) {
  gemm_sigloss_body<false>(nullptr, nullptr, A32, B32, la, lb, scale_p, bias_p,
                           pos_part, neg_part, cnt_part);
}

__global__ __launch_bounds__(256) void finalize_loss(
    const float* __restrict__ pos_part, const float* __restrict__ neg_part,
    const unsigned* __restrict__ cnt_part, float* __restrict__ out) {
  __shared__ float rp[4], rn[4];
  __shared__ unsigned rc[4];
  const int w = threadIdx.x >> 6;
  const int l = threadIdx.x & 63;
  float ps = 0.f, ns = 0.f;
  int pc = 0;
  for (int i = threadIdx.x; i < NPART; i += 256) {
    ps += pos_part[i];
    ns += neg_part[i];
    pc += (int)cnt_part[i];
  }
#pragma unroll
  for (int off = 32; off > 0; off >>= 1) {
    ps += __shfl_down(ps, off);
    ns += __shfl_down(ns, off);
    pc += __shfl_down(pc, off);
  }
  if (l == 0) { rp[w] = ps; rn[w] = ns; rc[w] = (unsigned)pc; }
  __syncthreads();
  if (threadIdx.x == 0) {
    double tp = (double)rp[0] + rp[1] + rp[2] + rp[3];
    double tn = (double)rn[0] + rn[1] + rn[2] + rn[3];
    long long tc = (long long)rc[0] + rc[1] + rc[2] + rc[3];
    double num_pos = (double)(tc > 1 ? tc : 1);
    long long negc = (long long)NN * MM - tc;
    double num_neg = (double)(negc > 1 ? negc : 1);
    out[0] = (float)(tp / num_pos + tn / num_neg * (double)(NN - 1));
  }
}

extern "C" void kernel_launch(void* const* d_in, const int* in_sizes, int n_in,
                              void* d_out, int out_size, void* d_ws, size_t ws_size,
                              hipStream_t stream) {
  const float* A32 = (const float*)d_in[0];
  const float* B32 = (const float*)d_in[1];
  const int* la = (const int*)d_in[2];
  const int* lb = (const int*)d_in[3];
  const float* scale_p = (const float*)d_in[4];
  const float* bias_p = (const float*)d_in[5];
  float* out = (float*)d_out;

  char* ws = (char*)d_ws;
  float* pos_part = (float*)ws;                       // 4096 f32
  float* neg_part = pos_part + NPART;                 // 4096 f32
  unsigned* cnt_part = (unsigned*)(neg_part + NPART); // 4096 u32
  unsigned short* Abf = (unsigned short*)(ws + 65536);
  unsigned short* Bbf = Abf + (size_t)NN * DD;

  const size_t need = 65536 + 2ull * (size_t)NN * DD * 2;
  const bool usebf = (ws_size >= need);

  if (usebf) {
    convert_both<<<2048, 256, 0, stream>>>(A32, B32, Abf, Bbf);
    gemm_sigloss_bf16ws<<<NPART, 256, 0, stream>>>(Abf, Bbf, la, lb, scale_p,
                                                   bias_p, pos_part, neg_part,
                                                   cnt_part);
  } else {
    gemm_sigloss_f32<<<NPART, 256, 0, stream>>>(A32, B32, la, lb, scale_p,
                                                bias_p, pos_part, neg_part,
                                                cnt_part);
  }
  finalize_loss<<<1, 256, 0, stream>>>(pos_part, neg_part, cnt_part, out);
}